// Round 3
// baseline (221.471 us; speedup 1.0000x reference)
//
#include <hip/hip_runtime.h>
#include <hip/hip_bf16.h>
#include <cstdint>
#include <cstddef>

// Problem constants
constexpr int T_TOK = 4096;   // B*S
constexpr int H_DIM = 1024;
constexpr int E_NUM = 8;
constexpr int I_DIM = 1024;
constexpr int F2    = 2048;   // 2*I
constexpr float ALPHA = 1.702f;
constexpr float LIMIT = 7.0f;
constexpr int BM = 128;       // GEMM row tile
constexpr int BK = 64;        // GEMM k tile
constexpr int MAXTILES = 72;  // >= sum(ceil(cnt_e/128)) worst case (71)

using u16    = unsigned short;
using bf16x8 = __attribute__((ext_vector_type(8))) __bf16;
using s16x8  = __attribute__((ext_vector_type(8))) short;
using f32x4  = __attribute__((ext_vector_type(4))) float;

// Workspace layout (bytes)
constexpr size_t WS_W1T  = 0;                        // [E][2][I][H] bf16 : 33,554,432
constexpr size_t WS_W2T  = 33554432;                 // [E][H][I]   bf16 : 16,777,216
constexpr size_t WS_ACT  = 50331648;                 // [8192][I]   bf16 : 16,777,216
constexpr size_t WS_ETOK = 67108864;                 // [E][T] int
constexpr size_t WS_EW   = 67239936;                 // [E][T] float
constexpr size_t WS_CNT  = 67371008;                 // [E] int
constexpr size_t WS_ROWB = 67371040;                 // [E] int
constexpr size_t WS_ASGN = 67371072;                 // [MAXTILES] int (1KB reserved)
constexpr size_t WS_TOPE = 67372096;                 // [T] int
constexpr size_t WS_TOPW = WS_TOPE + T_TOK * 4;      // [T] float2
constexpr size_t WS_XBF  = WS_TOPW + T_TOK * 8;      // [T][H] bf16 : 8,388,608
constexpr size_t WS_NEED = WS_XBF + (size_t)T_TOK * H_DIM * 2;

__device__ __forceinline__ u16 f2bf(float f) {
    union { float f; unsigned u; } v; v.f = f;
    return (u16)((v.u + 0x7FFFu + ((v.u >> 16) & 1u)) >> 16);   // RNE
}

__device__ __forceinline__ s16x8 pack8(float4 a, float4 b) {
    s16x8 r;
    r[0] = (short)f2bf(a.x); r[1] = (short)f2bf(a.y);
    r[2] = (short)f2bf(a.z); r[3] = (short)f2bf(a.w);
    r[4] = (short)f2bf(b.x); r[5] = (short)f2bf(b.y);
    r[6] = (short)f2bf(b.z); r[7] = (short)f2bf(b.w);
    return r;
}

// async global -> LDS, 16B per lane. LDS dest = wave-uniform base + lane*16.
__device__ __forceinline__ void gload16(const void* g, void* l) {
    __builtin_amdgcn_global_load_lds((const __attribute__((address_space(1))) unsigned*)g,
                                     (__attribute__((address_space(3))) unsigned*)l,
                                     16, 0, 0);
}

// ---------------------------------------------------------------------------
// x fp32 -> bf16 (once)
// ---------------------------------------------------------------------------
__global__ __launch_bounds__(256) void k_xbf(const float* __restrict__ x,
                                             u16* __restrict__ xbf) {
    const size_t i = ((size_t)blockIdx.x * 256 + threadIdx.x) * 8;
    float4 a = *(const float4*)(x + i);
    float4 b = *(const float4*)(x + i + 4);
    *(s16x8*)(xbf + i) = pack8(a, b);
}

// ---------------------------------------------------------------------------
// Transpose gate_up_proj [E][H][2I] fp32 -> [E][2][I][H] bf16 (de-interleave)
// ---------------------------------------------------------------------------
__global__ __launch_bounds__(256) void k_transpose_w1(const float* __restrict__ in,
                                                      u16* __restrict__ out) {
    __shared__ float tile[64][65];
    const int e = blockIdx.z, c0 = blockIdx.x * 64, h0 = blockIdx.y * 64;
    const int tid = threadIdx.x;
    const float* src = in + ((size_t)e * H_DIM + h0) * F2 + c0;
#pragma unroll
    for (int i = 0; i < 4; ++i) {
        int r = (tid >> 4) + i * 16, c = (tid & 15) * 4;
        float4 v = *(const float4*)(src + (size_t)r * F2 + c);
        tile[r][c] = v.x; tile[r][c + 1] = v.y; tile[r][c + 2] = v.z; tile[r][c + 3] = v.w;
    }
    __syncthreads();
    const int c = tid >> 2, hseg = (tid & 3) * 16;
    const int g = c & 1;
    const int f = (c0 + c) >> 1;
    u16* dst = out + (((size_t)e * 2 + g) * I_DIM + f) * H_DIM + h0 + hseg;
    s16x8 o0, o1;
#pragma unroll
    for (int j = 0; j < 8; ++j) o0[j] = (short)f2bf(tile[hseg + j][c]);
#pragma unroll
    for (int j = 0; j < 8; ++j) o1[j] = (short)f2bf(tile[hseg + 8 + j][c]);
    *(s16x8*)dst = o0;
    *(s16x8*)(dst + 8) = o1;
}

// ---------------------------------------------------------------------------
// Transpose down_proj [E][I][H] fp32 -> [E][H][I] bf16
// ---------------------------------------------------------------------------
__global__ __launch_bounds__(256) void k_transpose_w2(const float* __restrict__ in,
                                                      u16* __restrict__ out) {
    __shared__ float tile[64][65];
    const int e = blockIdx.z, h0 = blockIdx.x * 64, i0 = blockIdx.y * 64;
    const int tid = threadIdx.x;
    const float* src = in + ((size_t)e * I_DIM + i0) * H_DIM + h0;
#pragma unroll
    for (int i = 0; i < 4; ++i) {
        int r = (tid >> 4) + i * 16, c = (tid & 15) * 4;
        float4 v = *(const float4*)(src + (size_t)r * H_DIM + c);
        tile[r][c] = v.x; tile[r][c + 1] = v.y; tile[r][c + 2] = v.z; tile[r][c + 3] = v.w;
    }
    __syncthreads();
    const int c = tid >> 2, iseg = (tid & 3) * 16;
    u16* dst = out + ((size_t)e * H_DIM + h0 + c) * I_DIM + i0 + iseg;
    s16x8 o0, o1;
#pragma unroll
    for (int j = 0; j < 8; ++j) o0[j] = (short)f2bf(tile[iseg + j][c]);
#pragma unroll
    for (int j = 0; j < 8; ++j) o1[j] = (short)f2bf(tile[iseg + 8 + j][c]);
    *(s16x8*)dst = o0;
    *(s16x8*)(dst + 8) = o1;
}

// ---------------------------------------------------------------------------
// Router phase 1: fp32 logits, top-2, softmax. One wave per token. No atomics.
// ---------------------------------------------------------------------------
__global__ __launch_bounds__(256) void k_router_top2(const float* __restrict__ x,
                                                     const float* __restrict__ rw,
                                                     int* __restrict__ tope,
                                                     float2* __restrict__ topw) {
    const int wave = threadIdx.x >> 6, lane = threadIdx.x & 63;
    const int t = blockIdx.x * 4 + wave;
    const float* xr = x + (size_t)t * H_DIM;
    float acc[E_NUM];
#pragma unroll
    for (int e = 0; e < E_NUM; ++e) acc[e] = 0.f;
    for (int h = lane; h < H_DIM; h += 64) {
        float xv = xr[h];
        const float* r = rw + h * E_NUM;
#pragma unroll
        for (int e = 0; e < E_NUM; ++e) acc[e] += xv * r[e];
    }
#pragma unroll
    for (int e = 0; e < E_NUM; ++e) {
        float v = acc[e];
#pragma unroll
        for (int o = 32; o > 0; o >>= 1) v += __shfl_down(v, o);
        acc[e] = v;
    }
    if (lane == 0) {
        int e0 = 0; float v0 = acc[0];
#pragma unroll
        for (int e = 1; e < E_NUM; ++e) if (acc[e] > v0) { v0 = acc[e]; e0 = e; }
        int e1 = -1; float v1 = -3.4e38f;
#pragma unroll
        for (int e = 0; e < E_NUM; ++e) if (e != e0 && acc[e] > v1) { v1 = acc[e]; e1 = e; }
        float ew = expf(v1 - v0);
        float inv = 1.f / (1.f + ew);
        tope[t] = e0 | (e1 << 8);
        topw[t] = make_float2(inv, ew * inv);
    }
}

// ---------------------------------------------------------------------------
// Router phase 2: block-aggregated scatter (1 global atomic per expert/block).
// ---------------------------------------------------------------------------
__global__ __launch_bounds__(256) void k_router_scatter(const int* __restrict__ tope,
                                                        const float2* __restrict__ topw,
                                                        int* __restrict__ cnt,
                                                        int* __restrict__ ent_tok,
                                                        float* __restrict__ ent_w) {
    __shared__ int lcnt[E_NUM];
    __shared__ int gbase[E_NUM];
    const int tid = threadIdx.x;
    const int t = blockIdx.x * 256 + tid;
    if (tid < E_NUM) lcnt[tid] = 0;
    __syncthreads();
    const int pk = tope[t];
    const float2 w = topw[t];
    const int e0 = pk & 0xff, e1 = pk >> 8;
    const int o0 = atomicAdd(&lcnt[e0], 1);
    const int o1 = atomicAdd(&lcnt[e1], 1);
    __syncthreads();
    if (tid < E_NUM) gbase[tid] = atomicAdd(&cnt[tid], lcnt[tid]);
    __syncthreads();
    const int p0 = gbase[e0] + o0;
    const int p1 = gbase[e1] + o1;
    ent_tok[e0 * T_TOK + p0] = t; ent_w[e0 * T_TOK + p0] = w.x;
    ent_tok[e1 * T_TOK + p1] = t; ent_w[e1 * T_TOK + p1] = w.y;
}

// ---------------------------------------------------------------------------
// Schedule: counts -> row bases + tile assignment table (BM=128 tiles).
// ---------------------------------------------------------------------------
__global__ void k_schedule(const int* __restrict__ cnt, int* __restrict__ rowbase,
                           int* __restrict__ assign) {
    if (threadIdx.x == 0) {
        int rb = 0, na = 0;
        for (int e = 0; e < E_NUM; ++e) {
            rowbase[e] = rb;
            int nt = (cnt[e] + BM - 1) >> 7;
            for (int m = 0; m < nt; ++m) assign[na++] = (e << 16) | m;
            rb += cnt[e];
        }
        for (; na < MAXTILES; ++na) assign[na] = -1;
    }
}

// ---------------------------------------------------------------------------
// GEMM1: 128 entries x 64 act cols (128 B-rows: gate64|up64), BK=64.
// global_load_lds staging, both-sides XOR swizzle (slot ^= row&7, 16B slots).
// 4 waves as 2(M)x2(N): wave = 64 rows x 32 act cols.
// ---------------------------------------------------------------------------
__global__ __launch_bounds__(256) void k_gemm1(
    const u16* __restrict__ xbf, const u16* __restrict__ w1t,
    const float* __restrict__ bias, const int* __restrict__ ent_tok,
    const int* __restrict__ cnt, const int* __restrict__ rowbase,
    const int* __restrict__ assign, u16* __restrict__ act) {
    const int a = assign[blockIdx.x];
    if (a < 0) return;
    const int e = a >> 16, mt = a & 0xffff;
    const int j0 = blockIdx.y * 64;
    const int cs = cnt[e], r0 = mt * BM;
    __shared__ __align__(16) u16 As[BM * BK];    // [128][64] swizzled, 16KB
    __shared__ __align__(16) u16 Bs[128 * BK];   // [128][64] swizzled, 16KB
    const int tid = threadIdx.x, lane = tid & 63, wave = tid >> 6;
    // staging: per wave 4 instrs of 8 rows each; lane -> (row, swizzled k-slot)
    const int lrow8 = lane >> 3;                  // 0..7 (== row&7)
    const int slot = (lane & 7) ^ lrow8;          // inverse-swizzled source slot
    const u16* asrc[4]; const u16* bsrc[4]; u16* adst[4]; u16* bdst[4];
#pragma unroll
    for (int j = 0; j < 4; ++j) {
        const int lrow = wave * 32 + j * 8 + lrow8;
        const int aent = r0 + lrow;
        const int tok = (aent < cs) ? ent_tok[e * T_TOK + aent] : 0;
        asrc[j] = xbf + (size_t)tok * H_DIM + slot * 8;
        const int bg = lrow >> 6, bj = j0 + (lrow & 63);
        bsrc[j] = w1t + (((size_t)e * 2 + bg) * I_DIM + bj) * H_DIM + slot * 8;
        adst[j] = &As[(wave * 32 + j * 8) * BK];
        bdst[j] = &Bs[(wave * 32 + j * 8) * BK];
    }
    // compute-side read offsets (bytes, loop-invariant)
    const int wm = wave >> 1, wn = wave & 1;
    const int lcol = lane & 15, lk = lane >> 4;
    int aoff[4][2], goff[2][2], uoff[2][2];
#pragma unroll
    for (int mi = 0; mi < 4; ++mi) {
        const int row = wm * 64 + mi * 16 + lcol;
#pragma unroll
        for (int h = 0; h < 2; ++h)
            aoff[mi][h] = row * 128 + ((((h * 4) + lk) ^ (row & 7)) << 4);
    }
#pragma unroll
    for (int fj = 0; fj < 2; ++fj) {
        const int rg = wn * 32 + fj * 16 + lcol;
        const int ru = 64 + rg;
#pragma unroll
        for (int h = 0; h < 2; ++h) {
            goff[fj][h] = rg * 128 + ((((h * 4) + lk) ^ (rg & 7)) << 4);
            uoff[fj][h] = ru * 128 + ((((h * 4) + lk) ^ (ru & 7)) << 4);
        }
    }

    f32x4 accg[4][2], accu[4][2];
    const f32x4 z = {0.f, 0.f, 0.f, 0.f};
#pragma unroll
    for (int mi = 0; mi < 4; ++mi)
#pragma unroll
        for (int fj = 0; fj < 2; ++fj) { accg[mi][fj] = z; accu[mi][fj] = z; }

    const char* Ab = (const char*)As;
    const char* Bb = (const char*)Bs;
    for (int kb = 0; kb < H_DIM; kb += BK) {
#pragma unroll
        for (int j = 0; j < 4; ++j) gload16(asrc[j] + kb, adst[j]);
#pragma unroll
        for (int j = 0; j < 4; ++j) gload16(bsrc[j] + kb, bdst[j]);
        __syncthreads();   // waits vmcnt(0): tiles resident
#pragma unroll
        for (int h = 0; h < 2; ++h) {
            bf16x8 af[4], gf[2], uf[2];
#pragma unroll
            for (int mi = 0; mi < 4; ++mi) af[mi] = *(const bf16x8*)(Ab + aoff[mi][h]);
#pragma unroll
            for (int fj = 0; fj < 2; ++fj) {
                gf[fj] = *(const bf16x8*)(Bb + goff[fj][h]);
                uf[fj] = *(const bf16x8*)(Bb + uoff[fj][h]);
            }
#pragma unroll
            for (int mi = 0; mi < 4; ++mi)
#pragma unroll
                for (int fj = 0; fj < 2; ++fj) {
                    accg[mi][fj] = __builtin_amdgcn_mfma_f32_16x16x32_bf16(af[mi], gf[fj], accg[mi][fj], 0, 0, 0);
                    accu[mi][fj] = __builtin_amdgcn_mfma_f32_16x16x32_bf16(af[mi], uf[fj], accu[mi][fj], 0, 0, 0);
                }
        }
        __syncthreads();   // all reads done before next stage overwrites
    }
    // epilogue: clamp + GLU, store bf16 act
    const int rbase = rowbase[e];
#pragma unroll
    for (int mi = 0; mi < 4; ++mi) {
#pragma unroll
        for (int fj = 0; fj < 2; ++fj) {
            const int col = j0 + wn * 32 + fj * 16 + lcol;
            const float biasg = bias[e * F2 + 2 * col];
            const float biasu = bias[e * F2 + 2 * col + 1];
#pragma unroll
            for (int rg = 0; rg < 4; ++rg) {
                const int r = wm * 64 + mi * 16 + lk * 4 + rg;
                if (r0 + r < cs) {
                    float gv = accg[mi][fj][rg] + biasg;
                    float uv = accu[mi][fj][rg] + biasu;
                    gv = fminf(gv, LIMIT);
                    uv = fminf(fmaxf(uv, -LIMIT), LIMIT);
                    float glu = gv / (1.f + expf(-ALPHA * gv));
                    act[(size_t)(rbase + r0 + r) * I_DIM + col] = f2bf((uv + 1.f) * glu);
                }
            }
        }
    }
}

// ---------------------------------------------------------------------------
// GEMM2: 128 entries x 128 out cols, BK=64, same staging scheme.
// 4 waves as 2(M)x2(N): wave = 64 rows x 64 cols.
// ---------------------------------------------------------------------------
__global__ __launch_bounds__(256) void k_gemm2(
    const u16* __restrict__ act, const u16* __restrict__ w2t,
    const float* __restrict__ bias, const int* __restrict__ ent_tok,
    const float* __restrict__ ent_w, const int* __restrict__ cnt,
    const int* __restrict__ rowbase, const int* __restrict__ assign,
    float* __restrict__ out) {
    const int a = assign[blockIdx.x];
    if (a < 0) return;
    const int e = a >> 16, mt = a & 0xffff;
    const int n0 = blockIdx.y * 128;
    const int cs = cnt[e], r0 = mt * BM, rbase = rowbase[e];
    __shared__ __align__(16) u16 As[BM * BK];
    __shared__ __align__(16) u16 Bs[128 * BK];
    const int tid = threadIdx.x, lane = tid & 63, wave = tid >> 6;
    const int lrow8 = lane >> 3;
    const int slot = (lane & 7) ^ lrow8;
    const u16* asrc[4]; const u16* bsrc[4]; u16* adst[4]; u16* bdst[4];
#pragma unroll
    for (int j = 0; j < 4; ++j) {
        const int lrow = wave * 32 + j * 8 + lrow8;
        int arow = rbase + r0 + lrow;
        if (arow > 2 * T_TOK - 1) arow = 2 * T_TOK - 1;
        asrc[j] = act + (size_t)arow * I_DIM + slot * 8;
        bsrc[j] = w2t + ((size_t)e * H_DIM + n0 + lrow) * I_DIM + slot * 8;
        adst[j] = &As[(wave * 32 + j * 8) * BK];
        bdst[j] = &Bs[(wave * 32 + j * 8) * BK];
    }
    const int wm = wave >> 1, wn = wave & 1;
    const int lcol = lane & 15, lk = lane >> 4;
    int aoff[4][2], boff[4][2];
#pragma unroll
    for (int mi = 0; mi < 4; ++mi) {
        const int row = wm * 64 + mi * 16 + lcol;
        const int brow = wn * 64 + mi * 16 + lcol;
#pragma unroll
        for (int h = 0; h < 2; ++h) {
            aoff[mi][h] = row * 128 + ((((h * 4) + lk) ^ (row & 7)) << 4);
            boff[mi][h] = brow * 128 + ((((h * 4) + lk) ^ (brow & 7)) << 4);
        }
    }

    f32x4 acc[4][4];
    const f32x4 z = {0.f, 0.f, 0.f, 0.f};
#pragma unroll
    for (int mi = 0; mi < 4; ++mi)
#pragma unroll
        for (int fj = 0; fj < 4; ++fj) acc[mi][fj] = z;

    const char* Ab = (const char*)As;
    const char* Bb = (const char*)Bs;
    for (int kb = 0; kb < I_DIM; kb += BK) {
#pragma unroll
        for (int j = 0; j < 4; ++j) gload16(asrc[j] + kb, adst[j]);
#pragma unroll
        for (int j = 0; j < 4; ++j) gload16(bsrc[j] + kb, bdst[j]);
        __syncthreads();
#pragma unroll
        for (int h = 0; h < 2; ++h) {
            bf16x8 af[4], bf_[4];
#pragma unroll
            for (int mi = 0; mi < 4; ++mi) af[mi]  = *(const bf16x8*)(Ab + aoff[mi][h]);
#pragma unroll
            for (int fj = 0; fj < 4; ++fj) bf_[fj] = *(const bf16x8*)(Bb + boff[fj][h]);
#pragma unroll
            for (int mi = 0; mi < 4; ++mi)
#pragma unroll
                for (int fj = 0; fj < 4; ++fj)
                    acc[mi][fj] = __builtin_amdgcn_mfma_f32_16x16x32_bf16(af[mi], bf_[fj], acc[mi][fj], 0, 0, 0);
        }
        __syncthreads();
    }
#pragma unroll
    for (int mi = 0; mi < 4; ++mi) {
#pragma unroll
        for (int fj = 0; fj < 4; ++fj) {
            const int col = n0 + wn * 64 + fj * 16 + lcol;
            const float bv = bias[e * H_DIM + col];
#pragma unroll
            for (int rg = 0; rg < 4; ++rg) {
                const int r = wm * 64 + mi * 16 + lk * 4 + rg;
                if (r0 + r < cs) {
                    const int ent = e * T_TOK + r0 + r;
                    atomicAdd(&out[(size_t)ent_tok[ent] * H_DIM + col],
                              ent_w[ent] * (acc[mi][fj][rg] + bv));
                }
            }
        }
    }
}

// ---------------------------------------------------------------------------
extern "C" void kernel_launch(void* const* d_in, const int* in_sizes, int n_in,
                              void* d_out, int out_size, void* d_ws, size_t ws_size,
                              hipStream_t stream) {
    const float* x   = (const float*)d_in[0];
    const float* rw  = (const float*)d_in[1];
    const float* w1  = (const float*)d_in[2];
    const float* b1  = (const float*)d_in[3];
    const float* w2  = (const float*)d_in[4];
    const float* b2  = (const float*)d_in[5];
    float* out = (float*)d_out;
    char* ws = (char*)d_ws;

    if (ws_size < WS_NEED) return;

    u16*    W1T  = (u16*)(ws + WS_W1T);
    u16*    W2T  = (u16*)(ws + WS_W2T);
    u16*    ACT  = (u16*)(ws + WS_ACT);
    int*    ETOK = (int*)(ws + WS_ETOK);
    float*  EW   = (float*)(ws + WS_EW);
    int*    CNT  = (int*)(ws + WS_CNT);
    int*    ROWB = (int*)(ws + WS_ROWB);
    int*    ASGN = (int*)(ws + WS_ASGN);
    int*    TOPE = (int*)(ws + WS_TOPE);
    float2* TOPW = (float2*)(ws + WS_TOPW);
    u16*    XBF  = (u16*)(ws + WS_XBF);

    hipMemsetAsync(CNT, 0, E_NUM * sizeof(int), stream);
    hipMemsetAsync(out, 0, (size_t)T_TOK * H_DIM * sizeof(float), stream);

    k_xbf<<<T_TOK * H_DIM / 2048, 256, 0, stream>>>(x, XBF);
    k_transpose_w1<<<dim3(32, 16, 8), 256, 0, stream>>>(w1, W1T);
    k_transpose_w2<<<dim3(16, 16, 8), 256, 0, stream>>>(w2, W2T);
    k_router_top2<<<T_TOK / 4, 256, 0, stream>>>(x, rw, TOPE, TOPW);
    k_router_scatter<<<T_TOK / 256, 256, 0, stream>>>(TOPE, TOPW, CNT, ETOK, EW);
    k_schedule<<<1, 64, 0, stream>>>(CNT, ROWB, ASGN);
    k_gemm1<<<dim3(MAXTILES, 16), 256, 0, stream>>>(XBF, W1T, b1, ETOK, CNT, ROWB, ASGN, ACT);
    k_gemm2<<<dim3(MAXTILES, 8), 256, 0, stream>>>(ACT, W2T, b2, ETOK, EW, CNT, ROWB, ASGN, out);
}

// Round 4
// 207.042 us; speedup vs baseline: 1.0697x; 1.0697x over previous
//
#include <hip/hip_runtime.h>
#include <hip/hip_bf16.h>
#include <cstdint>
#include <cstddef>

// Problem constants
constexpr int T_TOK = 4096;   // B*S
constexpr int H_DIM = 1024;
constexpr int E_NUM = 8;
constexpr int I_DIM = 1024;
constexpr int F2    = 2048;   // 2*I
constexpr float ALPHA = 1.702f;
constexpr float LIMIT = 7.0f;
constexpr int BM = 256;       // GEMM row tile
constexpr int BK = 64;        // GEMM k tile
constexpr int NT1 = H_DIM / BK;  // 16 k-tiles (gemm1)
constexpr int NT2 = I_DIM / BK;  // 16 k-tiles (gemm2)
constexpr int MAXT = 40;      // >= sum(ceil(cnt_e/256)) worst case (39)

using u16    = unsigned short;
using bf16x8 = __attribute__((ext_vector_type(8))) __bf16;
using s16x8  = __attribute__((ext_vector_type(8))) short;
using f32x4  = __attribute__((ext_vector_type(4))) float;

// Workspace layout (bytes). DOWN aliases W1T (gemm1 is done with W1T before
// gemm2 writes DOWN; transposes rewrite W1T every call — deterministic).
constexpr size_t WS_W1T  = 0;                        // [E][2][I][H] bf16 : 33,554,432
constexpr size_t WS_DOWN = 0;                        // [8192][H] bf16 (alias)
constexpr size_t WS_W2T  = 33554432;                 // [E][H][I] bf16 : 16,777,216
constexpr size_t WS_ACT  = 50331648;                 // [8192][I] bf16 : 16,777,216
constexpr size_t WS_ETOK = 67108864;                 // [E][T] int
constexpr size_t WS_POS  = 67239936;                 // [T] int2
constexpr size_t WS_CNT  = 67272704;                 // [E] int
constexpr size_t WS_ROWB = 67272736;                 // [E] int
constexpr size_t WS_ASGN = 67272768;                 // [MAXT] int (1KB reserved)
constexpr size_t WS_TOPE = 67273792;                 // [T] int
constexpr size_t WS_TOPW = 67290176;                 // [T] float2
constexpr size_t WS_XBF  = 67322944;                 // [T][H] bf16 : 8,388,608
constexpr size_t WS_NEED = 75711552;

__device__ __forceinline__ u16 f2bf(float f) {
    union { float f; unsigned u; } v; v.f = f;
    return (u16)((v.u + 0x7FFFu + ((v.u >> 16) & 1u)) >> 16);   // RNE
}
__device__ __forceinline__ float bf2f(u16 u) {
    union { unsigned u; float f; } v; v.u = (unsigned)u << 16; return v.f;
}

__device__ __forceinline__ s16x8 pack8(float4 a, float4 b) {
    s16x8 r;
    r[0] = (short)f2bf(a.x); r[1] = (short)f2bf(a.y);
    r[2] = (short)f2bf(a.z); r[3] = (short)f2bf(a.w);
    r[4] = (short)f2bf(b.x); r[5] = (short)f2bf(b.y);
    r[6] = (short)f2bf(b.z); r[7] = (short)f2bf(b.w);
    return r;
}

// async global -> LDS, 16B per lane. LDS dest = wave-uniform base + lane*16.
__device__ __forceinline__ void gload16(const void* g, void* l) {
    __builtin_amdgcn_global_load_lds((const __attribute__((address_space(1))) unsigned*)g,
                                     (__attribute__((address_space(3))) unsigned*)l,
                                     16, 0, 0);
}

// counted-drain barrier: drain own stage loads + ds_reads, then raw barrier.
__device__ __forceinline__ void pipe_sync() {
    __builtin_amdgcn_sched_barrier(0);
    asm volatile("s_waitcnt vmcnt(0) lgkmcnt(0)" ::: "memory");
    __builtin_amdgcn_s_barrier();
    __builtin_amdgcn_sched_barrier(0);
}

// ---------------------------------------------------------------------------
// x fp32 -> bf16 (once)
// ---------------------------------------------------------------------------
__global__ __launch_bounds__(256) void k_xbf(const float* __restrict__ x,
                                             u16* __restrict__ xbf) {
    const size_t i = ((size_t)blockIdx.x * 256 + threadIdx.x) * 8;
    float4 a = *(const float4*)(x + i);
    float4 b = *(const float4*)(x + i + 4);
    *(s16x8*)(xbf + i) = pack8(a, b);
}

// ---------------------------------------------------------------------------
// Transpose gate_up_proj [E][H][2I] fp32 -> [E][2][I][H] bf16 (de-interleave)
// ---------------------------------------------------------------------------
__global__ __launch_bounds__(256) void k_transpose_w1(const float* __restrict__ in,
                                                      u16* __restrict__ out) {
    __shared__ float tile[64][65];
    const int e = blockIdx.z, c0 = blockIdx.x * 64, h0 = blockIdx.y * 64;
    const int tid = threadIdx.x;
    const float* src = in + ((size_t)e * H_DIM + h0) * F2 + c0;
#pragma unroll
    for (int i = 0; i < 4; ++i) {
        int r = (tid >> 4) + i * 16, c = (tid & 15) * 4;
        float4 v = *(const float4*)(src + (size_t)r * F2 + c);
        tile[r][c] = v.x; tile[r][c + 1] = v.y; tile[r][c + 2] = v.z; tile[r][c + 3] = v.w;
    }
    __syncthreads();
    const int c = tid >> 2, hseg = (tid & 3) * 16;
    const int g = c & 1;
    const int f = (c0 + c) >> 1;
    u16* dst = out + (((size_t)e * 2 + g) * I_DIM + f) * H_DIM + h0 + hseg;
    s16x8 o0, o1;
#pragma unroll
    for (int j = 0; j < 8; ++j) o0[j] = (short)f2bf(tile[hseg + j][c]);
#pragma unroll
    for (int j = 0; j < 8; ++j) o1[j] = (short)f2bf(tile[hseg + 8 + j][c]);
    *(s16x8*)dst = o0;
    *(s16x8*)(dst + 8) = o1;
}

// ---------------------------------------------------------------------------
// Transpose down_proj [E][I][H] fp32 -> [E][H][I] bf16
// ---------------------------------------------------------------------------
__global__ __launch_bounds__(256) void k_transpose_w2(const float* __restrict__ in,
                                                      u16* __restrict__ out) {
    __shared__ float tile[64][65];
    const int e = blockIdx.z, h0 = blockIdx.x * 64, i0 = blockIdx.y * 64;
    const int tid = threadIdx.x;
    const float* src = in + ((size_t)e * I_DIM + i0) * H_DIM + h0;
#pragma unroll
    for (int i = 0; i < 4; ++i) {
        int r = (tid >> 4) + i * 16, c = (tid & 15) * 4;
        float4 v = *(const float4*)(src + (size_t)r * H_DIM + c);
        tile[r][c] = v.x; tile[r][c + 1] = v.y; tile[r][c + 2] = v.z; tile[r][c + 3] = v.w;
    }
    __syncthreads();
    const int c = tid >> 2, iseg = (tid & 3) * 16;
    u16* dst = out + ((size_t)e * H_DIM + h0 + c) * I_DIM + i0 + iseg;
    s16x8 o0, o1;
#pragma unroll
    for (int j = 0; j < 8; ++j) o0[j] = (short)f2bf(tile[iseg + j][c]);
#pragma unroll
    for (int j = 0; j < 8; ++j) o1[j] = (short)f2bf(tile[iseg + 8 + j][c]);
    *(s16x8*)dst = o0;
    *(s16x8*)(dst + 8) = o1;
}

// ---------------------------------------------------------------------------
// Router phase 1: fp32 logits, top-2, softmax. One wave per token. No atomics.
// ---------------------------------------------------------------------------
__global__ __launch_bounds__(256) void k_router_top2(const float* __restrict__ x,
                                                     const float* __restrict__ rw,
                                                     int* __restrict__ tope,
                                                     float2* __restrict__ topw) {
    const int wave = threadIdx.x >> 6, lane = threadIdx.x & 63;
    const int t = blockIdx.x * 4 + wave;
    const float* xr = x + (size_t)t * H_DIM;
    float acc[E_NUM];
#pragma unroll
    for (int e = 0; e < E_NUM; ++e) acc[e] = 0.f;
    for (int h = lane; h < H_DIM; h += 64) {
        float xv = xr[h];
        const float* r = rw + h * E_NUM;
#pragma unroll
        for (int e = 0; e < E_NUM; ++e) acc[e] += xv * r[e];
    }
#pragma unroll
    for (int e = 0; e < E_NUM; ++e) {
        float v = acc[e];
#pragma unroll
        for (int o = 32; o > 0; o >>= 1) v += __shfl_down(v, o);
        acc[e] = v;
    }
    if (lane == 0) {
        int e0 = 0; float v0 = acc[0];
#pragma unroll
        for (int e = 1; e < E_NUM; ++e) if (acc[e] > v0) { v0 = acc[e]; e0 = e; }
        int e1 = -1; float v1 = -3.4e38f;
#pragma unroll
        for (int e = 0; e < E_NUM; ++e) if (e != e0 && acc[e] > v1) { v1 = acc[e]; e1 = e; }
        float ew = expf(v1 - v0);
        float inv = 1.f / (1.f + ew);
        tope[t] = e0 | (e1 << 8);
        topw[t] = make_float2(inv, ew * inv);
    }
}

// ---------------------------------------------------------------------------
// Router phase 2: block-aggregated scatter (1 global atomic per expert/block).
// Also records each token's position in its expert lists (for combine).
// ---------------------------------------------------------------------------
__global__ __launch_bounds__(256) void k_router_scatter(const int* __restrict__ tope,
                                                        int* __restrict__ cnt,
                                                        int* __restrict__ ent_tok,
                                                        int2* __restrict__ pos) {
    __shared__ int lcnt[E_NUM];
    __shared__ int gbase[E_NUM];
    const int tid = threadIdx.x;
    const int t = blockIdx.x * 256 + tid;
    if (tid < E_NUM) lcnt[tid] = 0;
    __syncthreads();
    const int pk = tope[t];
    const int e0 = pk & 0xff, e1 = pk >> 8;
    const int o0 = atomicAdd(&lcnt[e0], 1);
    const int o1 = atomicAdd(&lcnt[e1], 1);
    __syncthreads();
    if (tid < E_NUM) gbase[tid] = atomicAdd(&cnt[tid], lcnt[tid]);
    __syncthreads();
    const int p0 = gbase[e0] + o0;
    const int p1 = gbase[e1] + o1;
    ent_tok[e0 * T_TOK + p0] = t;
    ent_tok[e1 * T_TOK + p1] = t;
    pos[t] = make_int2(p0, p1);
}

// ---------------------------------------------------------------------------
// Schedule: counts -> row bases + tile assignment table (BM=256 tiles).
// ---------------------------------------------------------------------------
__global__ void k_schedule(const int* __restrict__ cnt, int* __restrict__ rowbase,
                           int* __restrict__ assign) {
    if (threadIdx.x == 0) {
        int rb = 0, na = 0;
        for (int e = 0; e < E_NUM; ++e) {
            rowbase[e] = rb;
            int nt = (cnt[e] + BM - 1) >> 8;
            for (int m = 0; m < nt; ++m) assign[na++] = (e << 16) | m;
            rb += cnt[e];
        }
        for (; na < MAXT; ++na) assign[na] = -1;
    }
}

// ---------------------------------------------------------------------------
// GEMM1: 256 entries x 128 act cols (256 B-rows: gate128|up128), BK=64.
// 512 thr / 8 waves (2M x 4N). Double-buffered LDS (128KB), stage-before-
// compute + counted drain after compute (2-phase pipeline).
// ---------------------------------------------------------------------------
__global__ __launch_bounds__(512, 2) void k_gemm1(
    const u16* __restrict__ xbf, const u16* __restrict__ w1t,
    const float* __restrict__ bias, const int* __restrict__ ent_tok,
    const int* __restrict__ cnt, const int* __restrict__ rowbase,
    const int* __restrict__ assign, u16* __restrict__ act) {
    const int a = assign[blockIdx.y];
    if (a < 0) return;
    const int e = a >> 16, mt = a & 0xffff;
    const int f0 = blockIdx.x * 128;
    const int cs = cnt[e], r0 = mt * BM;
    __shared__ __align__(16) u16 As[2][BM * BK];   // 2 x 32KB
    __shared__ __align__(16) u16 Bs[2][BM * BK];   // 2 x 32KB
    const int tid = threadIdx.x, lane = tid & 63, wv = tid >> 6;
    const int lr8 = lane >> 3, slot = (lane & 7) ^ lr8;   // inverse-swizzled src slot
    const u16* asrc[4]; const u16* bsrc[4]; int doff[4];
#pragma unroll
    for (int j = 0; j < 4; ++j) {
        const int row = j * 64 + wv * 8 + lr8;
        const int aent = r0 + row;
        const int tok = (aent < cs) ? ent_tok[e * T_TOK + aent] : 0;
        asrc[j] = xbf + (size_t)tok * H_DIM + slot * 8;
        const int g = row >> 7;                       // 0: gate rows, 1: up rows
        const int f = f0 + (row & 127);
        bsrc[j] = w1t + (((size_t)e * 2 + g) * I_DIM + f) * H_DIM + slot * 8;
        doff[j] = (j * 64 + wv * 8) * BK;
    }
    const int wm = wv >> 2, wn = wv & 3;
    const int lcol = lane & 15, lk = lane >> 4;
    int aoff[8], goff[2], uoff[2];
#pragma unroll
    for (int mi = 0; mi < 8; ++mi) {
        const int r = wm * 128 + mi * 16 + lcol;
        aoff[mi] = r * 128 + ((lk ^ (r & 7)) << 4);
    }
#pragma unroll
    for (int fj = 0; fj < 2; ++fj) {
        const int rg_ = wn * 32 + fj * 16 + lcol;
        const int ru = 128 + rg_;
        goff[fj] = rg_ * 128 + ((lk ^ (rg_ & 7)) << 4);
        uoff[fj] = ru * 128 + ((lk ^ (ru & 7)) << 4);
    }
    f32x4 accg[8][2], accu[8][2];
    const f32x4 z = {0.f, 0.f, 0.f, 0.f};
#pragma unroll
    for (int mi = 0; mi < 8; ++mi) {
        accg[mi][0] = z; accg[mi][1] = z; accu[mi][0] = z; accu[mi][1] = z;
    }
    // prologue: stage tile 0
#pragma unroll
    for (int j = 0; j < 4; ++j) {
        gload16(asrc[j], &As[0][doff[j]]);
        gload16(bsrc[j], &Bs[0][doff[j]]);
    }
    pipe_sync();
    int cur = 0;
    for (int t = 0; t < NT1; ++t) {
        if (t + 1 < NT1) {                      // issue next-tile stage FIRST
            const int kn = (t + 1) * BK;
            u16* Ad = As[cur ^ 1]; u16* Bd = Bs[cur ^ 1];
#pragma unroll
            for (int j = 0; j < 4; ++j) {
                gload16(asrc[j] + kn, Ad + doff[j]);
                gload16(bsrc[j] + kn, Bd + doff[j]);
            }
        }
        const char* Ab = (const char*)As[cur];
        const char* Bb = (const char*)Bs[cur];
#pragma unroll
        for (int h = 0; h < 2; ++h) {
            const int hx = h << 6;
            bf16x8 af[8];
#pragma unroll
            for (int mi = 0; mi < 8; ++mi) af[mi] = *(const bf16x8*)(Ab + (aoff[mi] ^ hx));
            const bf16x8 gf0 = *(const bf16x8*)(Bb + (goff[0] ^ hx));
            const bf16x8 gf1 = *(const bf16x8*)(Bb + (goff[1] ^ hx));
            const bf16x8 uf0 = *(const bf16x8*)(Bb + (uoff[0] ^ hx));
            const bf16x8 uf1 = *(const bf16x8*)(Bb + (uoff[1] ^ hx));
#pragma unroll
            for (int mi = 0; mi < 8; ++mi) {
                accg[mi][0] = __builtin_amdgcn_mfma_f32_16x16x32_bf16(af[mi], gf0, accg[mi][0], 0, 0, 0);
                accu[mi][0] = __builtin_amdgcn_mfma_f32_16x16x32_bf16(af[mi], uf0, accu[mi][0], 0, 0, 0);
                accg[mi][1] = __builtin_amdgcn_mfma_f32_16x16x32_bf16(af[mi], gf1, accg[mi][1], 0, 0, 0);
                accu[mi][1] = __builtin_amdgcn_mfma_f32_16x16x32_bf16(af[mi], uf1, accu[mi][1], 0, 0, 0);
            }
        }
        pipe_sync();                            // drains next-tile stage (hidden under compute)
        cur ^= 1;
    }
    // epilogue: clamp + GLU, store bf16 act
    const int rbase = rowbase[e];
#pragma unroll
    for (int mi = 0; mi < 8; ++mi) {
#pragma unroll
        for (int fj = 0; fj < 2; ++fj) {
            const int col = f0 + wn * 32 + fj * 16 + lcol;
            const float bg_ = bias[e * F2 + 2 * col];
            const float bu_ = bias[e * F2 + 2 * col + 1];
#pragma unroll
            for (int rg = 0; rg < 4; ++rg) {
                const int r = wm * 128 + mi * 16 + lk * 4 + rg;
                if (r0 + r < cs) {
                    float gv = accg[mi][fj][rg] + bg_;
                    float uv = accu[mi][fj][rg] + bu_;
                    gv = fminf(gv, LIMIT);
                    uv = fminf(fmaxf(uv, -LIMIT), LIMIT);
                    const float glu = gv / (1.f + expf(-ALPHA * gv));
                    act[(size_t)(rbase + r0 + r) * I_DIM + col] = f2bf((uv + 1.f) * glu);
                }
            }
        }
    }
}

// ---------------------------------------------------------------------------
// GEMM2: 256 entries x 128 out cols, BK=64, same 2-phase pipeline (96KB LDS).
// Stores raw per-entry result to DOWN (bf16) — no atomics; combine applies
// routing weight + bias.
// ---------------------------------------------------------------------------
__global__ __launch_bounds__(512, 2) void k_gemm2(
    const u16* __restrict__ act, const u16* __restrict__ w2t,
    const int* __restrict__ cnt, const int* __restrict__ rowbase,
    const int* __restrict__ assign, u16* __restrict__ down) {
    const int a = assign[blockIdx.y];
    if (a < 0) return;
    const int e = a >> 16, mt = a & 0xffff;
    const int n0 = blockIdx.x * 128;
    const int cs = cnt[e], r0 = mt * BM, rbase = rowbase[e];
    __shared__ __align__(16) u16 As[2][BM * BK];    // 2 x 32KB
    __shared__ __align__(16) u16 Bs[2][128 * BK];   // 2 x 16KB
    const int tid = threadIdx.x, lane = tid & 63, wv = tid >> 6;
    const int lr8 = lane >> 3, slot = (lane & 7) ^ lr8;
    const u16* asrc[4]; int adoff[4];
    const u16* bsrc[2]; int bdoff[2];
#pragma unroll
    for (int j = 0; j < 4; ++j) {
        const int row = j * 64 + wv * 8 + lr8;
        int ar = rbase + r0 + row;
        if (ar > 2 * T_TOK - 1) ar = 2 * T_TOK - 1;
        asrc[j] = act + (size_t)ar * I_DIM + slot * 8;
        adoff[j] = (j * 64 + wv * 8) * BK;
    }
#pragma unroll
    for (int j = 0; j < 2; ++j) {
        const int row = j * 64 + wv * 8 + lr8;
        bsrc[j] = w2t + ((size_t)e * H_DIM + n0 + row) * I_DIM + slot * 8;
        bdoff[j] = (j * 64 + wv * 8) * BK;
    }
    const int wm = wv >> 2, wn = wv & 3;
    const int lcol = lane & 15, lk = lane >> 4;
    int aoff[8], boff[2];
#pragma unroll
    for (int mi = 0; mi < 8; ++mi) {
        const int r = wm * 128 + mi * 16 + lcol;
        aoff[mi] = r * 128 + ((lk ^ (r & 7)) << 4);
    }
#pragma unroll
    for (int fj = 0; fj < 2; ++fj) {
        const int br = wn * 32 + fj * 16 + lcol;
        boff[fj] = br * 128 + ((lk ^ (br & 7)) << 4);
    }
    f32x4 acc[8][2];
    const f32x4 z = {0.f, 0.f, 0.f, 0.f};
#pragma unroll
    for (int mi = 0; mi < 8; ++mi) { acc[mi][0] = z; acc[mi][1] = z; }
#pragma unroll
    for (int j = 0; j < 4; ++j) gload16(asrc[j], &As[0][adoff[j]]);
#pragma unroll
    for (int j = 0; j < 2; ++j) gload16(bsrc[j], &Bs[0][bdoff[j]]);
    pipe_sync();
    int cur = 0;
    for (int t = 0; t < NT2; ++t) {
        if (t + 1 < NT2) {
            const int kn = (t + 1) * BK;
            u16* Ad = As[cur ^ 1]; u16* Bd = Bs[cur ^ 1];
#pragma unroll
            for (int j = 0; j < 4; ++j) gload16(asrc[j] + kn, Ad + adoff[j]);
#pragma unroll
            for (int j = 0; j < 2; ++j) gload16(bsrc[j] + kn, Bd + bdoff[j]);
        }
        const char* Ab = (const char*)As[cur];
        const char* Bb = (const char*)Bs[cur];
#pragma unroll
        for (int h = 0; h < 2; ++h) {
            const int hx = h << 6;
            bf16x8 af[8];
#pragma unroll
            for (int mi = 0; mi < 8; ++mi) af[mi] = *(const bf16x8*)(Ab + (aoff[mi] ^ hx));
            const bf16x8 bf0 = *(const bf16x8*)(Bb + (boff[0] ^ hx));
            const bf16x8 bf1 = *(const bf16x8*)(Bb + (boff[1] ^ hx));
#pragma unroll
            for (int mi = 0; mi < 8; ++mi) {
                acc[mi][0] = __builtin_amdgcn_mfma_f32_16x16x32_bf16(af[mi], bf0, acc[mi][0], 0, 0, 0);
                acc[mi][1] = __builtin_amdgcn_mfma_f32_16x16x32_bf16(af[mi], bf1, acc[mi][1], 0, 0, 0);
            }
        }
        pipe_sync();
        cur ^= 1;
    }
#pragma unroll
    for (int mi = 0; mi < 8; ++mi) {
#pragma unroll
        for (int fj = 0; fj < 2; ++fj) {
            const int col = n0 + wn * 32 + fj * 16 + lcol;
#pragma unroll
            for (int rg = 0; rg < 4; ++rg) {
                const int r = wm * 128 + mi * 16 + lk * 4 + rg;
                if (r0 + r < cs)
                    down[(size_t)(rbase + r0 + r) * H_DIM + col] = f2bf(acc[mi][fj][rg]);
            }
        }
    }
}

// ---------------------------------------------------------------------------
// Combine: out[t][h] = w0*(down[row0][h]+b2[e0][h]) + w1*(down[row1][h]+b2[e1][h])
// ---------------------------------------------------------------------------
__global__ __launch_bounds__(256) void k_combine(
    const int* __restrict__ tope, const float2* __restrict__ topw,
    const int2* __restrict__ pos, const int* __restrict__ rowb,
    const float* __restrict__ b2, const u16* __restrict__ down,
    float* __restrict__ out) {
    const int t = blockIdx.x;
    const int c = threadIdx.x * 4;
    const int pk = tope[t];
    const int e0 = pk & 0xff, e1 = pk >> 8;
    const int2 pp = pos[t];
    const float2 w = topw[t];
    const size_t ro0 = (size_t)(rowb[e0] + pp.x) * H_DIM;
    const size_t ro1 = (size_t)(rowb[e1] + pp.y) * H_DIM;
    ushort4 d0 = *(const ushort4*)(down + ro0 + c);
    ushort4 d1 = *(const ushort4*)(down + ro1 + c);
    float4 bb0 = *(const float4*)(b2 + e0 * H_DIM + c);
    float4 bb1 = *(const float4*)(b2 + e1 * H_DIM + c);
    float4 o;
    o.x = w.x * (bf2f(d0.x) + bb0.x) + w.y * (bf2f(d1.x) + bb1.x);
    o.y = w.x * (bf2f(d0.y) + bb0.y) + w.y * (bf2f(d1.y) + bb1.y);
    o.z = w.x * (bf2f(d0.z) + bb0.z) + w.y * (bf2f(d1.z) + bb1.z);
    o.w = w.x * (bf2f(d0.w) + bb0.w) + w.y * (bf2f(d1.w) + bb1.w);
    *(float4*)(out + (size_t)t * H_DIM + c) = o;
}

// ---------------------------------------------------------------------------
extern "C" void kernel_launch(void* const* d_in, const int* in_sizes, int n_in,
                              void* d_out, int out_size, void* d_ws, size_t ws_size,
                              hipStream_t stream) {
    const float* x   = (const float*)d_in[0];
    const float* rw  = (const float*)d_in[1];
    const float* w1  = (const float*)d_in[2];
    const float* b1  = (const float*)d_in[3];
    const float* w2  = (const float*)d_in[4];
    const float* b2  = (const float*)d_in[5];
    float* out = (float*)d_out;
    char* ws = (char*)d_ws;

    if (ws_size < WS_NEED) return;

    u16*    W1T  = (u16*)(ws + WS_W1T);
    u16*    DOWN = (u16*)(ws + WS_DOWN);   // aliases W1T (safe: used after gemm1)
    u16*    W2T  = (u16*)(ws + WS_W2T);
    u16*    ACT  = (u16*)(ws + WS_ACT);
    int*    ETOK = (int*)(ws + WS_ETOK);
    int2*   POS  = (int2*)(ws + WS_POS);
    int*    CNT  = (int*)(ws + WS_CNT);
    int*    ROWB = (int*)(ws + WS_ROWB);
    int*    ASGN = (int*)(ws + WS_ASGN);
    int*    TOPE = (int*)(ws + WS_TOPE);
    float2* TOPW = (float2*)(ws + WS_TOPW);
    u16*    XBF  = (u16*)(ws + WS_XBF);

    hipMemsetAsync(CNT, 0, E_NUM * sizeof(int), stream);

    k_xbf<<<T_TOK * H_DIM / 2048, 256, 0, stream>>>(x, XBF);
    k_transpose_w1<<<dim3(32, 16, 8), 256, 0, stream>>>(w1, W1T);
    k_transpose_w2<<<dim3(16, 16, 8), 256, 0, stream>>>(w2, W2T);
    k_router_top2<<<T_TOK / 4, 256, 0, stream>>>(x, rw, TOPE, TOPW);
    k_router_scatter<<<T_TOK / 256, 256, 0, stream>>>(TOPE, CNT, ETOK, POS);
    k_schedule<<<1, 64, 0, stream>>>(CNT, ROWB, ASGN);
    k_gemm1<<<dim3(8, MAXT), 512, 0, stream>>>(XBF, W1T, b1, ETOK, CNT, ROWB, ASGN, ACT);
    k_gemm2<<<dim3(8, MAXT), 512, 0, stream>>>(ACT, W2T, CNT, ROWB, ASGN, DOWN);
    k_combine<<<T_TOK, 256, 0, stream>>>(TOPE, TOPW, POS, ROWB, b2, DOWN, out);
}

// Round 5
// 166.588 us; speedup vs baseline: 1.3294x; 1.2428x over previous
//
#include <hip/hip_runtime.h>
#include <hip/hip_bf16.h>
#include <cstdint>
#include <cstddef>

// Problem constants
constexpr int T_TOK = 4096;   // B*S
constexpr int H_DIM = 1024;
constexpr int E_NUM = 8;
constexpr int I_DIM = 1024;
constexpr int F2    = 2048;   // 2*I
constexpr float ALPHA = 1.702f;
constexpr float LIMIT = 7.0f;
constexpr int BM = 128;       // GEMM row tile
constexpr int BK = 32;        // GEMM k tile
constexpr int NT = 32;        // k-steps (K=1024)
constexpr int MAXT = 72;      // >= sum(ceil(cnt_e/128)) worst case (71)

using u16    = unsigned short;
using bf16x8 = __attribute__((ext_vector_type(8))) __bf16;
using s16x8  = __attribute__((ext_vector_type(8))) short;
using f32x4  = __attribute__((ext_vector_type(4))) float;

// Workspace layout (bytes). DOWN aliases W1T (gemm1 finishes with W1T before
// gemm2 writes DOWN; transposes rewrite W1T every call — deterministic).
constexpr size_t WS_W1T  = 0;                        // [E][2][I][H] bf16 : 33,554,432
constexpr size_t WS_DOWN = 0;                        // [8192][H] bf16 (alias)
constexpr size_t WS_W2T  = 33554432;                 // [E][H][I] bf16 : 16,777,216
constexpr size_t WS_ACT  = 50331648;                 // [8192][I] bf16 : 16,777,216
constexpr size_t WS_ETOK = 67108864;                 // [E][T] int
constexpr size_t WS_POS  = 67239936;                 // [T] int2
constexpr size_t WS_CNT  = 67272704;                 // [E] int
constexpr size_t WS_ROWB = 67272736;                 // [E] int
constexpr size_t WS_ASGN = 67272768;                 // [MAXT] int (1KB reserved)
constexpr size_t WS_TOPE = 67273792;                 // [T] int
constexpr size_t WS_TOPW = 67290176;                 // [T] float2
constexpr size_t WS_XBF  = 67322944;                 // [T][H] bf16 : 8,388,608
constexpr size_t WS_NEED = 75711552;

__device__ __forceinline__ u16 f2bf(float f) {
    union { float f; unsigned u; } v; v.f = f;
    return (u16)((v.u + 0x7FFFu + ((v.u >> 16) & 1u)) >> 16);   // RNE
}
__device__ __forceinline__ float bf2f(u16 u) {
    union { unsigned u; float f; } v; v.u = (unsigned)u << 16; return v.f;
}

__device__ __forceinline__ s16x8 pack8(float4 a, float4 b) {
    s16x8 r;
    r[0] = (short)f2bf(a.x); r[1] = (short)f2bf(a.y);
    r[2] = (short)f2bf(a.z); r[3] = (short)f2bf(a.w);
    r[4] = (short)f2bf(b.x); r[5] = (short)f2bf(b.y);
    r[6] = (short)f2bf(b.z); r[7] = (short)f2bf(b.w);
    return r;
}

// async global -> LDS, 16B per lane. LDS dest = wave-uniform base + lane*16.
__device__ __forceinline__ void gload16(const void* g, void* l) {
    __builtin_amdgcn_global_load_lds((const __attribute__((address_space(1))) unsigned*)g,
                                     (__attribute__((address_space(3))) unsigned*)l,
                                     16, 0, 0);
}

// drain own stage loads + ds ops, then raw barrier.
__device__ __forceinline__ void pipe_sync() {
    __builtin_amdgcn_sched_barrier(0);
    asm volatile("s_waitcnt vmcnt(0) lgkmcnt(0)" ::: "memory");
    __builtin_amdgcn_s_barrier();
    __builtin_amdgcn_sched_barrier(0);
}

// ---------------------------------------------------------------------------
// x fp32 -> bf16 (once)
// ---------------------------------------------------------------------------
__global__ __launch_bounds__(256) void k_xbf(const float* __restrict__ x,
                                             u16* __restrict__ xbf) {
    const size_t i = ((size_t)blockIdx.x * 256 + threadIdx.x) * 8;
    float4 a = *(const float4*)(x + i);
    float4 b = *(const float4*)(x + i + 4);
    *(s16x8*)(xbf + i) = pack8(a, b);
}

// ---------------------------------------------------------------------------
// Transpose gate_up_proj [E][H][2I] fp32 -> [E][2][I][H] bf16 (de-interleave)
// ---------------------------------------------------------------------------
__global__ __launch_bounds__(256) void k_transpose_w1(const float* __restrict__ in,
                                                      u16* __restrict__ out) {
    __shared__ float tile[64][65];
    const int e = blockIdx.z, c0 = blockIdx.x * 64, h0 = blockIdx.y * 64;
    const int tid = threadIdx.x;
    const float* src = in + ((size_t)e * H_DIM + h0) * F2 + c0;
#pragma unroll
    for (int i = 0; i < 4; ++i) {
        int r = (tid >> 4) + i * 16, c = (tid & 15) * 4;
        float4 v = *(const float4*)(src + (size_t)r * F2 + c);
        tile[r][c] = v.x; tile[r][c + 1] = v.y; tile[r][c + 2] = v.z; tile[r][c + 3] = v.w;
    }
    __syncthreads();
    const int c = tid >> 2, hseg = (tid & 3) * 16;
    const int g = c & 1;
    const int f = (c0 + c) >> 1;
    u16* dst = out + (((size_t)e * 2 + g) * I_DIM + f) * H_DIM + h0 + hseg;
    s16x8 o0, o1;
#pragma unroll
    for (int j = 0; j < 8; ++j) o0[j] = (short)f2bf(tile[hseg + j][c]);
#pragma unroll
    for (int j = 0; j < 8; ++j) o1[j] = (short)f2bf(tile[hseg + 8 + j][c]);
    *(s16x8*)dst = o0;
    *(s16x8*)(dst + 8) = o1;
}

// ---------------------------------------------------------------------------
// Transpose down_proj [E][I][H] fp32 -> [E][H][I] bf16
// ---------------------------------------------------------------------------
__global__ __launch_bounds__(256) void k_transpose_w2(const float* __restrict__ in,
                                                      u16* __restrict__ out) {
    __shared__ float tile[64][65];
    const int e = blockIdx.z, h0 = blockIdx.x * 64, i0 = blockIdx.y * 64;
    const int tid = threadIdx.x;
    const float* src = in + ((size_t)e * I_DIM + i0) * H_DIM + h0;
#pragma unroll
    for (int i = 0; i < 4; ++i) {
        int r = (tid >> 4) + i * 16, c = (tid & 15) * 4;
        float4 v = *(const float4*)(src + (size_t)r * H_DIM + c);
        tile[r][c] = v.x; tile[r][c + 1] = v.y; tile[r][c + 2] = v.z; tile[r][c + 3] = v.w;
    }
    __syncthreads();
    const int c = tid >> 2, iseg = (tid & 3) * 16;
    u16* dst = out + ((size_t)e * H_DIM + h0 + c) * I_DIM + i0 + iseg;
    s16x8 o0, o1;
#pragma unroll
    for (int j = 0; j < 8; ++j) o0[j] = (short)f2bf(tile[iseg + j][c]);
#pragma unroll
    for (int j = 0; j < 8; ++j) o1[j] = (short)f2bf(tile[iseg + 8 + j][c]);
    *(s16x8*)dst = o0;
    *(s16x8*)(dst + 8) = o1;
}

// ---------------------------------------------------------------------------
// Router phase 1: fp32 logits, top-2, softmax. One wave per token. No atomics.
// ---------------------------------------------------------------------------
__global__ __launch_bounds__(256) void k_router_top2(const float* __restrict__ x,
                                                     const float* __restrict__ rw,
                                                     int* __restrict__ tope,
                                                     float2* __restrict__ topw) {
    const int wave = threadIdx.x >> 6, lane = threadIdx.x & 63;
    const int t = blockIdx.x * 4 + wave;
    const float* xr = x + (size_t)t * H_DIM;
    float acc[E_NUM];
#pragma unroll
    for (int e = 0; e < E_NUM; ++e) acc[e] = 0.f;
    for (int h = lane; h < H_DIM; h += 64) {
        float xv = xr[h];
        const float* r = rw + h * E_NUM;
#pragma unroll
        for (int e = 0; e < E_NUM; ++e) acc[e] += xv * r[e];
    }
#pragma unroll
    for (int e = 0; e < E_NUM; ++e) {
        float v = acc[e];
#pragma unroll
        for (int o = 32; o > 0; o >>= 1) v += __shfl_down(v, o);
        acc[e] = v;
    }
    if (lane == 0) {
        int e0 = 0; float v0 = acc[0];
#pragma unroll
        for (int e = 1; e < E_NUM; ++e) if (acc[e] > v0) { v0 = acc[e]; e0 = e; }
        int e1 = -1; float v1 = -3.4e38f;
#pragma unroll
        for (int e = 0; e < E_NUM; ++e) if (e != e0 && acc[e] > v1) { v1 = acc[e]; e1 = e; }
        float ew = expf(v1 - v0);
        float inv = 1.f / (1.f + ew);
        tope[t] = e0 | (e1 << 8);
        topw[t] = make_float2(inv, ew * inv);
    }
}

// ---------------------------------------------------------------------------
// Router phase 2: block-aggregated scatter (1 global atomic per expert/block).
// Also records each token's position in its expert lists (for combine).
// ---------------------------------------------------------------------------
__global__ __launch_bounds__(256) void k_router_scatter(const int* __restrict__ tope,
                                                        int* __restrict__ cnt,
                                                        int* __restrict__ ent_tok,
                                                        int2* __restrict__ pos) {
    __shared__ int lcnt[E_NUM];
    __shared__ int gbase[E_NUM];
    const int tid = threadIdx.x;
    const int t = blockIdx.x * 256 + tid;
    if (tid < E_NUM) lcnt[tid] = 0;
    __syncthreads();
    const int pk = tope[t];
    const int e0 = pk & 0xff, e1 = pk >> 8;
    const int o0 = atomicAdd(&lcnt[e0], 1);
    const int o1 = atomicAdd(&lcnt[e1], 1);
    __syncthreads();
    if (tid < E_NUM) gbase[tid] = atomicAdd(&cnt[tid], lcnt[tid]);
    __syncthreads();
    const int p0 = gbase[e0] + o0;
    const int p1 = gbase[e1] + o1;
    ent_tok[e0 * T_TOK + p0] = t;
    ent_tok[e1 * T_TOK + p1] = t;
    pos[t] = make_int2(p0, p1);
}

// ---------------------------------------------------------------------------
// Schedule: counts -> row bases + tile assignment table (BM=128 tiles).
// ---------------------------------------------------------------------------
__global__ void k_schedule(const int* __restrict__ cnt, int* __restrict__ rowbase,
                           int* __restrict__ assign) {
    if (threadIdx.x == 0) {
        int rb = 0, na = 0;
        for (int e = 0; e < E_NUM; ++e) {
            rowbase[e] = rb;
            int nt = (cnt[e] + BM - 1) >> 7;
            for (int m = 0; m < nt; ++m) assign[na++] = (e << 16) | m;
            rb += cnt[e];
        }
        for (; na < MAXT; ++na) assign[na] = -1;
    }
}

// ---------------------------------------------------------------------------
// GEMM1: 128 entries x 64 act-cols (B-tile: [gate64 | up64] rows), BK=32.
// 256 thr / 4 waves (2Mx2N), wave = 64 rows x (32 act-cols x {g,u}).
// Double-buffered 32KB LDS, stage-ahead 2-phase, 3 blocks/CU.
// Swizzle: 4 slots of 16B per row, slot ^= row&3 (both sides).
// ---------------------------------------------------------------------------
__global__ __launch_bounds__(256, 3) void k_gemm1(
    const u16* __restrict__ xbf, const u16* __restrict__ w1t,
    const float* __restrict__ bias, const int* __restrict__ ent_tok,
    const int* __restrict__ cnt, const int* __restrict__ rowbase,
    const int* __restrict__ assign, u16* __restrict__ act) {
    const int a = assign[blockIdx.y];
    if (a < 0) return;
    const int e = a >> 16, mt = a & 0xffff;
    const int j0 = blockIdx.x * 64;           // act-col base
    const int cs = cnt[e], r0 = mt * BM;
    __shared__ __align__(16) u16 As[2][BM * BK];   // 2 x 8KB
    __shared__ __align__(16) u16 Bs[2][BM * BK];   // 2 x 8KB
    const int tid = threadIdx.x, lane = tid & 63, wv = tid >> 6;
    const int lr = lane >> 2;                       // row-in-16 (0..15)
    const int sm = (lane & 3) ^ (lr & 3);           // inverse-swizzled src slot
    // staging: per thread 2 A-instr + 2 B-instr; instr j covers 16 rows
    const u16* asrc[2]; const u16* bsrc[2]; int dofs[2];
#pragma unroll
    for (int j = 0; j < 2; ++j) {
        const int row = wv * 32 + j * 16 + lr;
        const int aent = r0 + row;
        const int tok = (aent < cs) ? ent_tok[e * T_TOK + aent] : 0;
        asrc[j] = xbf + (size_t)tok * H_DIM + sm * 8;
        const int g = row >> 6;                     // 0: gate rows, 1: up rows
        const int f = j0 + (row & 63);
        bsrc[j] = w1t + (((size_t)e * 2 + g) * I_DIM + f) * H_DIM + sm * 8;
        dofs[j] = (wv * 32 + j * 16) * BK;
    }
    // compute-side byte offsets (loop-invariant)
    const int wm = wv >> 1, wn = wv & 1;
    const int lcol = lane & 15, lk = lane >> 4;
    int aoff[4], goff[2], uoff[2];
#pragma unroll
    for (int mi = 0; mi < 4; ++mi) {
        const int r = wm * 64 + mi * 16 + lcol;
        aoff[mi] = r * 64 + ((lk ^ (r & 3)) << 4);
    }
#pragma unroll
    for (int nj = 0; nj < 2; ++nj) {
        const int rg_ = wn * 32 + nj * 16 + lcol;
        const int ru  = 64 + rg_;
        goff[nj] = rg_ * 64 + ((lk ^ (rg_ & 3)) << 4);
        uoff[nj] = ru  * 64 + ((lk ^ (ru  & 3)) << 4);
    }
    f32x4 ag[4][2], au[4][2];
    const f32x4 z = {0.f, 0.f, 0.f, 0.f};
#pragma unroll
    for (int mi = 0; mi < 4; ++mi) { ag[mi][0] = z; ag[mi][1] = z; au[mi][0] = z; au[mi][1] = z; }
    // prologue: stage k-tile 0
#pragma unroll
    for (int j = 0; j < 2; ++j) {
        gload16(asrc[j], &As[0][dofs[j]]);
        gload16(bsrc[j], &Bs[0][dofs[j]]);
    }
    pipe_sync();
    int cur = 0;
    for (int t = 0; t < NT; ++t) {
        if (t + 1 < NT) {                      // issue next-tile stage FIRST
            const int kn = (t + 1) * BK;
            u16* Ad = As[cur ^ 1]; u16* Bd = Bs[cur ^ 1];
#pragma unroll
            for (int j = 0; j < 2; ++j) {
                gload16(asrc[j] + kn, Ad + dofs[j]);
                gload16(bsrc[j] + kn, Bd + dofs[j]);
            }
        }
        const char* Ab = (const char*)As[cur];
        const char* Bb = (const char*)Bs[cur];
        bf16x8 af[4];
#pragma unroll
        for (int mi = 0; mi < 4; ++mi) af[mi] = *(const bf16x8*)(Ab + aoff[mi]);
        const bf16x8 g0 = *(const bf16x8*)(Bb + goff[0]);
        const bf16x8 g1 = *(const bf16x8*)(Bb + goff[1]);
        const bf16x8 u0 = *(const bf16x8*)(Bb + uoff[0]);
        const bf16x8 u1 = *(const bf16x8*)(Bb + uoff[1]);
#pragma unroll
        for (int mi = 0; mi < 4; ++mi) {
            ag[mi][0] = __builtin_amdgcn_mfma_f32_16x16x32_bf16(af[mi], g0, ag[mi][0], 0, 0, 0);
            au[mi][0] = __builtin_amdgcn_mfma_f32_16x16x32_bf16(af[mi], u0, au[mi][0], 0, 0, 0);
            ag[mi][1] = __builtin_amdgcn_mfma_f32_16x16x32_bf16(af[mi], g1, ag[mi][1], 0, 0, 0);
            au[mi][1] = __builtin_amdgcn_mfma_f32_16x16x32_bf16(af[mi], u1, au[mi][1], 0, 0, 0);
        }
        pipe_sync();                           // next-tile stage drained (hidden under compute)
        cur ^= 1;
    }
    // epilogue: clamp + GLU, store bf16 act
    const int rbase = rowbase[e];
#pragma unroll
    for (int mi = 0; mi < 4; ++mi) {
#pragma unroll
        for (int nj = 0; nj < 2; ++nj) {
            const int col = j0 + wn * 32 + nj * 16 + lcol;
            const float bg_ = bias[e * F2 + 2 * col];
            const float bu_ = bias[e * F2 + 2 * col + 1];
#pragma unroll
            for (int rg = 0; rg < 4; ++rg) {
                const int r = wm * 64 + mi * 16 + lk * 4 + rg;
                if (r0 + r < cs) {
                    float gv = ag[mi][nj][rg] + bg_;
                    float uv = au[mi][nj][rg] + bu_;
                    gv = fminf(gv, LIMIT);
                    uv = fminf(fmaxf(uv, -LIMIT), LIMIT);
                    const float glu = gv / (1.f + expf(-ALPHA * gv));
                    act[(size_t)(rbase + r0 + r) * I_DIM + col] = f2bf((uv + 1.f) * glu);
                }
            }
        }
    }
}

// ---------------------------------------------------------------------------
// GEMM2: 128 entries x 128 out-cols, BK=32, same structure; writes raw DOWN
// (no atomics; combine applies routing weight + bias).
// ---------------------------------------------------------------------------
__global__ __launch_bounds__(256, 3) void k_gemm2(
    const u16* __restrict__ act, const u16* __restrict__ w2t,
    const int* __restrict__ cnt, const int* __restrict__ rowbase,
    const int* __restrict__ assign, u16* __restrict__ down) {
    const int a = assign[blockIdx.y];
    if (a < 0) return;
    const int e = a >> 16, mt = a & 0xffff;
    const int n0 = blockIdx.x * 128;
    const int cs = cnt[e], r0 = mt * BM, rbase = rowbase[e];
    __shared__ __align__(16) u16 As[2][BM * BK];
    __shared__ __align__(16) u16 Bs[2][BM * BK];
    const int tid = threadIdx.x, lane = tid & 63, wv = tid >> 6;
    const int lr = lane >> 2;
    const int sm = (lane & 3) ^ (lr & 3);
    const u16* asrc[2]; const u16* bsrc[2]; int dofs[2];
#pragma unroll
    for (int j = 0; j < 2; ++j) {
        const int row = wv * 32 + j * 16 + lr;
        int ar = rbase + r0 + row;
        if (ar > 2 * T_TOK - 1) ar = 2 * T_TOK - 1;
        asrc[j] = act + (size_t)ar * I_DIM + sm * 8;
        bsrc[j] = w2t + ((size_t)e * H_DIM + n0 + row) * I_DIM + sm * 8;
        dofs[j] = (wv * 32 + j * 16) * BK;
    }
    const int wm = wv >> 1, wn = wv & 1;
    const int lcol = lane & 15, lk = lane >> 4;
    int aoff[4], boff[4];
#pragma unroll
    for (int mi = 0; mi < 4; ++mi) {
        const int r = wm * 64 + mi * 16 + lcol;
        const int b = wn * 64 + mi * 16 + lcol;
        aoff[mi] = r * 64 + ((lk ^ (r & 3)) << 4);
        boff[mi] = b * 64 + ((lk ^ (b & 3)) << 4);
    }
    f32x4 acc[4][4];
    const f32x4 z = {0.f, 0.f, 0.f, 0.f};
#pragma unroll
    for (int mi = 0; mi < 4; ++mi)
#pragma unroll
        for (int nj = 0; nj < 4; ++nj) acc[mi][nj] = z;
#pragma unroll
    for (int j = 0; j < 2; ++j) {
        gload16(asrc[j], &As[0][dofs[j]]);
        gload16(bsrc[j], &Bs[0][dofs[j]]);
    }
    pipe_sync();
    int cur = 0;
    for (int t = 0; t < NT; ++t) {
        if (t + 1 < NT) {
            const int kn = (t + 1) * BK;
            u16* Ad = As[cur ^ 1]; u16* Bd = Bs[cur ^ 1];
#pragma unroll
            for (int j = 0; j < 2; ++j) {
                gload16(asrc[j] + kn, Ad + dofs[j]);
                gload16(bsrc[j] + kn, Bd + dofs[j]);
            }
        }
        const char* Ab = (const char*)As[cur];
        const char* Bb = (const char*)Bs[cur];
        bf16x8 af[4], bf_[4];
#pragma unroll
        for (int mi = 0; mi < 4; ++mi) af[mi]  = *(const bf16x8*)(Ab + aoff[mi]);
#pragma unroll
        for (int nj = 0; nj < 4; ++nj) bf_[nj] = *(const bf16x8*)(Bb + boff[nj]);
#pragma unroll
        for (int mi = 0; mi < 4; ++mi)
#pragma unroll
            for (int nj = 0; nj < 4; ++nj)
                acc[mi][nj] = __builtin_amdgcn_mfma_f32_16x16x32_bf16(af[mi], bf_[nj], acc[mi][nj], 0, 0, 0);
        pipe_sync();
        cur ^= 1;
    }
#pragma unroll
    for (int mi = 0; mi < 4; ++mi) {
#pragma unroll
        for (int nj = 0; nj < 4; ++nj) {
            const int col = n0 + wn * 64 + nj * 16 + lcol;
#pragma unroll
            for (int rg = 0; rg < 4; ++rg) {
                const int r = wm * 64 + mi * 16 + lk * 4 + rg;
                if (r0 + r < cs)
                    down[(size_t)(rbase + r0 + r) * H_DIM + col] = f2bf(acc[mi][nj][rg]);
            }
        }
    }
}

// ---------------------------------------------------------------------------
// Combine: out[t][h] = w0*(down[row0][h]+b2[e0][h]) + w1*(down[row1][h]+b2[e1][h])
// ---------------------------------------------------------------------------
__global__ __launch_bounds__(256) void k_combine(
    const int* __restrict__ tope, const float2* __restrict__ topw,
    const int2* __restrict__ pos, const int* __restrict__ rowb,
    const float* __restrict__ b2, const u16* __restrict__ down,
    float* __restrict__ out) {
    const int t = blockIdx.x;
    const int c = threadIdx.x * 4;
    const int pk = tope[t];
    const int e0 = pk & 0xff, e1 = pk >> 8;
    const int2 pp = pos[t];
    const float2 w = topw[t];
    const size_t ro0 = (size_t)(rowb[e0] + pp.x) * H_DIM;
    const size_t ro1 = (size_t)(rowb[e1] + pp.y) * H_DIM;
    ushort4 d0 = *(const ushort4*)(down + ro0 + c);
    ushort4 d1 = *(const ushort4*)(down + ro1 + c);
    float4 bb0 = *(const float4*)(b2 + e0 * H_DIM + c);
    float4 bb1 = *(const float4*)(b2 + e1 * H_DIM + c);
    float4 o;
    o.x = w.x * (bf2f(d0.x) + bb0.x) + w.y * (bf2f(d1.x) + bb1.x);
    o.y = w.x * (bf2f(d0.y) + bb0.y) + w.y * (bf2f(d1.y) + bb1.y);
    o.z = w.x * (bf2f(d0.z) + bb0.z) + w.y * (bf2f(d1.z) + bb1.z);
    o.w = w.x * (bf2f(d0.w) + bb0.w) + w.y * (bf2f(d1.w) + bb1.w);
    *(float4*)(out + (size_t)t * H_DIM + c) = o;
}

// ---------------------------------------------------------------------------
extern "C" void kernel_launch(void* const* d_in, const int* in_sizes, int n_in,
                              void* d_out, int out_size, void* d_ws, size_t ws_size,
                              hipStream_t stream) {
    const float* x   = (const float*)d_in[0];
    const float* rw  = (const float*)d_in[1];
    const float* w1  = (const float*)d_in[2];
    const float* b1  = (const float*)d_in[3];
    const float* w2  = (const float*)d_in[4];
    const float* b2  = (const float*)d_in[5];
    float* out = (float*)d_out;
    char* ws = (char*)d_ws;

    if (ws_size < WS_NEED) return;

    u16*    W1T  = (u16*)(ws + WS_W1T);
    u16*    DOWN = (u16*)(ws + WS_DOWN);   // aliases W1T (safe: used after gemm1)
    u16*    W2T  = (u16*)(ws + WS_W2T);
    u16*    ACT  = (u16*)(ws + WS_ACT);
    int*    ETOK = (int*)(ws + WS_ETOK);
    int2*   POS  = (int2*)(ws + WS_POS);
    int*    CNT  = (int*)(ws + WS_CNT);
    int*    ROWB = (int*)(ws + WS_ROWB);
    int*    ASGN = (int*)(ws + WS_ASGN);
    int*    TOPE = (int*)(ws + WS_TOPE);
    float2* TOPW = (float2*)(ws + WS_TOPW);
    u16*    XBF  = (u16*)(ws + WS_XBF);

    hipMemsetAsync(CNT, 0, E_NUM * sizeof(int), stream);

    k_xbf<<<T_TOK * H_DIM / 2048, 256, 0, stream>>>(x, XBF);
    k_transpose_w1<<<dim3(32, 16, 8), 256, 0, stream>>>(w1, W1T);
    k_transpose_w2<<<dim3(16, 16, 8), 256, 0, stream>>>(w2, W2T);
    k_router_top2<<<T_TOK / 4, 256, 0, stream>>>(x, rw, TOPE, TOPW);
    k_router_scatter<<<T_TOK / 256, 256, 0, stream>>>(TOPE, CNT, ETOK, POS);
    k_schedule<<<1, 64, 0, stream>>>(CNT, ROWB, ASGN);
    k_gemm1<<<dim3(16, MAXT), 256, 0, stream>>>(XBF, W1T, b1, ETOK, CNT, ROWB, ASGN, ACT);
    k_gemm2<<<dim3(8, MAXT), 256, 0, stream>>>(ACT, W2T, CNT, ROWB, ASGN, DOWN);
    k_combine<<<T_TOK, 256, 0, stream>>>(TOPE, TOPW, POS, ROWB, b2, DOWN, out);
}